// Round 2
// baseline (174.385 us; speedup 1.0000x reference)
//
#include <hip/hip_runtime.h>
#include <hip/hip_cooperative_groups.h>
#include <hip/hip_bf16.h>
#include <math.h>

namespace cg = cooperative_groups;

typedef __hip_bfloat16 bf16;
typedef short s8v __attribute__((ext_vector_type(8)));   // 8 bf16 (4 VGPRs)
typedef float f4v __attribute__((ext_vector_type(4)));   // MFMA acc

__device__ __forceinline__ float b2f(bf16 v) { return __bfloat162float(v); }

template <bool F32>
__device__ __forceinline__ float ld(const void* p, int i) {
  if (F32) return ((const float*)p)[i];
  return b2f(((const bf16*)p)[i]);
}

// 8 consecutive elems as a bf16x8 MFMA fragment (f32: 2 float4 + cvt).
template <bool F32>
__device__ __forceinline__ s8v ldfrag(const void* p, size_t i) {
  if (F32) {
    const float* f = (const float*)p + i;
    float4 u = *reinterpret_cast<const float4*>(f);
    float4 v = *reinterpret_cast<const float4*>(f + 4);
    s8v r;
    bf16 t;
    t = __float2bfloat16(u.x); r[0] = *(short*)&t;
    t = __float2bfloat16(u.y); r[1] = *(short*)&t;
    t = __float2bfloat16(u.z); r[2] = *(short*)&t;
    t = __float2bfloat16(u.w); r[3] = *(short*)&t;
    t = __float2bfloat16(v.x); r[4] = *(short*)&t;
    t = __float2bfloat16(v.y); r[5] = *(short*)&t;
    t = __float2bfloat16(v.z); r[6] = *(short*)&t;
    t = __float2bfloat16(v.w); r[7] = *(short*)&t;
    return r;
  }
  return *reinterpret_cast<const s8v*>((const bf16*)p + i);
}

__device__ __forceinline__ float sigm(float x) {
  return 0.5f * (1.0f + tanhf(0.5f * x));
}

// Wave-uniform (and grid-uniform) dtype detect (validated R2-R7 prior session).
__device__ __forceinline__ bool detect_f32(const void* xabs) {
  unsigned short v = ((const unsigned short*)xabs)[threadIdx.x & 63];
  int ex = (v >> 7) & 0xFF;
  return __ballot(ex >= 0x93) != 0ull;
}

template <bool F32>
__device__ __forceinline__ void cvt_f4(const void* src, bf16* __restrict__ dst,
                                       int i4) {
  if (F32) {
    float4 v = reinterpret_cast<const float4*>(src)[i4];
    bf16 t[4] = {__float2bfloat16(v.x), __float2bfloat16(v.y),
                 __float2bfloat16(v.z), __float2bfloat16(v.w)};
    reinterpret_cast<uint2*>(dst)[i4] = *reinterpret_cast<uint2*>(t);
  } else {
    reinterpret_cast<uint2*>(dst)[i4] = reinterpret_cast<const uint2*>(src)[i4];
  }
}

// ---------------------------------------------------------------------------
// Single cooperative kernel, 256 blocks x 256 threads (1 block/CU).
// Phase A (per block): weight cvt (<=1 f4/thread) | zgemm tile of
//   Z = h0 @ Wsoc^T (64m x 256e, MFMA) | neighbor-list build | emb/h0 -> Xb.
// grid.sync()
// Phase B (per block = 4 n's): Z gather -> pooling -> gates MFMA -> LSTM ->
//   out MFMA.
// LDS: [0,32K) G f32[16][512] (aliases lists[4][1024] during gather)
//      Xb bf16[16][XS], Hb bf16[16][HS]
// ---------------------------------------------------------------------------
#define XS 264
#define HS 136

template <bool F32>
__device__ __forceinline__ void run_all(
    const void* xabs, const void* h0, const void* Wemb, const void* bemb,
    const void* Wsoc, const void* bsoc, const void* Wih, const void* Whh,
    const void* bih, const void* bhh, const void* c0, const void* Wout,
    const void* bout, bf16* __restrict__ Z, bf16* Wih_b, bf16* Whh_b,
    bf16* Wout_b, void* out, char* smem, const cg::grid_group& grid) {
  float* G   = (float*)smem;           // [16][512] (phase B, after gather)
  int* lists = (int*)smem;             // [4][1024] (phase A build, B consume)
  bf16* Xb   = (bf16*)(smem + 32768);  // [16][XS]
  bf16* Hb   = (bf16*)(smem + 32768 + 16 * XS * 2);  // [16][HS]
  const int tid = threadIdx.x;
  const int wave = tid >> 6, lane = tid & 63;
  const int r16 = lane & 15, quad = lane >> 4;
  const int bx = blockIdx.x;

  // ===================== phase A (Z-independent + Z production) ============
  // Folded weight conversion: Wih 16384 f4 | Whh 16384 f4 | Wout 3840 f4.
  // Boundaries are multiples of 256 -> branch is block-uniform.
  const int t4 = bx * 256 + tid;
  if (t4 < 16384)
    cvt_f4<F32>(Wih, Wih_b, t4);
  else if (t4 < 32768)
    cvt_f4<F32>(Whh, Whh_b, t4 - 16384);
  else if (t4 < 36608)
    cvt_f4<F32>(Wout, Wout_b, t4 - 32768);

  // zgemm A-fragments (issue loads early; latency hides under list build)
  const int mt = bx & 15;               // 16 m-tiles of 64 rows
  const int g  = (bx >> 4) * 4 + wave;  // 64 g's
  s8v afr[4][4];  // [ms][kq]
#pragma unroll
  for (int ms = 0; ms < 4; ++ms)
#pragma unroll
    for (int kq = 0; kq < 4; ++kq)
      afr[ms][kq] = ldfrag<F32>(
          h0, (size_t)(mt * 64 + ms * 16 + r16) * 128 + kq * 32 + quad * 8);

  // neighbor-list build (depends only on xabs)
  const int n = bx * 4 + wave;
  const float xn = ld<F32>(xabs, 2 * n);
  const float yn = ld<F32>(xabs, 2 * n + 1);
  const float tx = xn - 0.2f, ty = yn - 0.2f;
  int* mylist = lists + wave * 1024;
  int cnt = 0;
  for (int c = 0; c < 16; ++c) {
    const int m = c * 64 + lane;
    float dx = ld<F32>(xabs, 2 * m) - tx;
    float dy = ld<F32>(xabs, 2 * m + 1) - ty;
    int cx = (int)floorf(dx / 0.4f * 8.0f);
    int cy = (int)floorf(dy / 0.4f * 8.0f);
    bool valid = (dx >= 0.f) & (dx < 0.4f) & (dy >= 0.f) & (dy < 0.4f) &
                 (cx >= 0) & (cx < 8) & (cy >= 0) & (cy < 8) & (m != n);
    unsigned long long msk = __ballot(valid);
    if (valid) {
      int pos = cnt + __popcll(msk & ((1ull << lane) - 1ull));
      mylist[pos] = (m << 6) | (cx + cy * 8);
    }
    cnt += __popcll(msk);
  }

  // zgemm compute + Z store
  f4v acc[4][4];  // [ms][t]
#pragma unroll
  for (int ms = 0; ms < 4; ++ms)
#pragma unroll
    for (int t = 0; t < 4; ++t) acc[ms][t] = (f4v){0.f, 0.f, 0.f, 0.f};
#pragma unroll
  for (int t = 0; t < 4; ++t) {
#pragma unroll
    for (int kq = 0; kq < 4; ++kq) {
      s8v bfr = ldfrag<F32>(
          Wsoc, (size_t)(t * 16 + r16) * 8192 + g * 128 + kq * 32 + quad * 8);
#pragma unroll
      for (int ms = 0; ms < 4; ++ms)
        acc[ms][t] = __builtin_amdgcn_mfma_f32_16x16x32_bf16(afr[ms][kq], bfr,
                                                             acc[ms][t], 0, 0, 0);
    }
  }
#pragma unroll
  for (int ms = 0; ms < 4; ++ms)
#pragma unroll
    for (int t = 0; t < 4; ++t)
#pragma unroll
      for (int reg = 0; reg < 4; ++reg)
        Z[(size_t)(mt * 64 + ms * 16 + quad * 4 + reg) * 4096 + g * 64 +
          t * 16 + r16] = __float2bfloat16(acc[ms][t][reg]);

  // Z-independent Xb/Hb staging
  for (int idx = 4 * XS + tid; idx < 16 * XS; idx += 256)
    Xb[idx] = __float2bfloat16(0.f);
  for (int idx = 4 * HS + tid; idx < 16 * HS; idx += 256)
    Hb[idx] = __float2bfloat16(0.f);
  float emb = fmaxf(ld<F32>(Wemb, lane * 2) * xn +
                        ld<F32>(Wemb, lane * 2 + 1) * yn + ld<F32>(bemb, lane),
                    0.f);
  Xb[wave * XS + lane] = __float2bfloat16(emb);
  Xb[wave * XS + 128 + lane] = __float2bfloat16(ld<F32>(h0, n * 128 + lane));
  Xb[wave * XS + 192 + lane] =
      __float2bfloat16(ld<F32>(h0, n * 128 + 64 + lane));

  grid.sync();  // Z complete and device-visible

  // ===================== phase B (Z consumption) ===========================
  float s[16];
#pragma unroll
  for (int u = 0; u < 16; ++u) s[u] = 0.f;
  int i = 0;
  for (; i + 16 <= cnt; i += 16) {
    int e[16];
#pragma unroll
    for (int u = 0; u < 16; ++u) e[u] = mylist[i + u];
#pragma unroll
    for (int u = 0; u < 16; ++u)
      s[u] += b2f(Z[(size_t)(e[u] >> 6) * 4096 + (e[u] & 63) * 64 + lane]);
  }
  for (; i + 4 <= cnt; i += 4) {
    int e[4];
#pragma unroll
    for (int u = 0; u < 4; ++u) e[u] = mylist[i + u];
#pragma unroll
    for (int u = 0; u < 4; ++u)
      s[u] += b2f(Z[(size_t)(e[u] >> 6) * 4096 + (e[u] & 63) * 64 + lane]);
  }
  for (; i < cnt; ++i) {
    int e0 = mylist[i];
    s[0] += b2f(Z[(size_t)(e0 >> 6) * 4096 + (e0 & 63) * 64 + lane]);
  }
#pragma unroll
  for (int u = 0; u < 8; ++u) s[u] += s[u + 8];
  float pool = ((s[0] + s[1]) + (s[2] + s[3])) + ((s[4] + s[5]) + (s[6] + s[7]));
  pool = fmaxf(pool + ld<F32>(bsoc, lane), 0.f);
  Xb[wave * XS + 64 + lane] = __float2bfloat16(pool);
  __syncthreads();  // lists dead; G live from here

  // ---- gates MFMA ----
  s8v xfr[8];
#pragma unroll
  for (int kq = 0; kq < 8; ++kq)
    xfr[kq] = *reinterpret_cast<const s8v*>(&Xb[r16 * XS + kq * 32 + quad * 8]);
  const int j0w = wave * 128;
  f4v bacc[8];
#pragma unroll
  for (int jt = 0; jt < 8; ++jt) bacc[jt] = (f4v){0.f, 0.f, 0.f, 0.f};
#pragma unroll
  for (int jt = 0; jt < 8; ++jt) {
    int j = j0w + jt * 16 + r16;
#pragma unroll
    for (int kq = 0; kq < 4; ++kq) {
      s8v bfr = *reinterpret_cast<const s8v*>(
          &Wih_b[(size_t)j * 128 + kq * 32 + quad * 8]);
      bacc[jt] = __builtin_amdgcn_mfma_f32_16x16x32_bf16(xfr[kq], bfr, bacc[jt],
                                                         0, 0, 0);
    }
#pragma unroll
    for (int kq = 0; kq < 4; ++kq) {
      s8v bfr = *reinterpret_cast<const s8v*>(
          &Whh_b[(size_t)j * 128 + kq * 32 + quad * 8]);
      bacc[jt] = __builtin_amdgcn_mfma_f32_16x16x32_bf16(xfr[kq + 4], bfr,
                                                         bacc[jt], 0, 0, 0);
    }
  }
#pragma unroll
  for (int jt = 0; jt < 8; ++jt) {
    int j = j0w + jt * 16 + r16;
    float bias = ld<F32>(bih, j) + ld<F32>(bhh, j);
#pragma unroll
    for (int reg = 0; reg < 4; ++reg)
      G[(quad * 4 + reg) * 512 + j] = bacc[jt][reg] + bias;
  }
  __syncthreads();

  // ---- LSTM elementwise ----
  for (int idx = tid; idx < 512; idx += 256) {
    int m = idx >> 7, tt = idx & 127;
    float ig = G[m * 512 + tt], fg = G[m * 512 + 128 + tt];
    float gg = G[m * 512 + 256 + tt], og = G[m * 512 + 384 + tt];
    float c = sigm(fg) * ld<F32>(c0, (bx * 4 + m) * 128 + tt) +
              sigm(ig) * tanhf(gg);
    Hb[m * HS + tt] = __float2bfloat16(sigm(og) * tanhf(c));
  }
  __syncthreads();

  // ---- out MFMA ----
  s8v hfr[4];
#pragma unroll
  for (int kq = 0; kq < 4; ++kq)
    hfr[kq] = *reinterpret_cast<const s8v*>(&Hb[r16 * HS + kq * 32 + quad * 8]);
#pragma unroll
  for (int jt2 = 0; jt2 < 2; ++jt2) {
    int j = wave * 32 + jt2 * 16 + r16;
    int jj = j < 120 ? j : 119;
    f4v oacc = (f4v){0.f, 0.f, 0.f, 0.f};
#pragma unroll
    for (int kq = 0; kq < 4; ++kq) {
      s8v bfr = *reinterpret_cast<const s8v*>(
          &Wout_b[(size_t)jj * 128 + kq * 32 + quad * 8]);
      oacc = __builtin_amdgcn_mfma_f32_16x16x32_bf16(hfr[kq], bfr, oacc, 0, 0, 0);
    }
    if (j < 120 && quad == 0) {
      float bo = ld<F32>(bout, j);
      int kk = j / 20, mm = j % 20;
#pragma unroll
      for (int reg = 0; reg < 4; ++reg) {
        int oi = kk * 20480 + (bx * 4 + reg) * 20 + mm;
        float val = oacc[reg] + bo;
        if (F32) ((float*)out)[oi] = val;
        else     ((bf16*)out)[oi] = __float2bfloat16(val);
      }
    }
  }
}

__global__ __launch_bounds__(256, 1) void k_all(
    const void* xabs, const void* h0, const void* Wemb, const void* bemb,
    const void* Wsoc, const void* bsoc, const void* Wih, const void* Whh,
    const void* bih, const void* bhh, const void* c0, const void* Wout,
    const void* bout, bf16* Z, bf16* Wih_b, bf16* Whh_b, bf16* Wout_b,
    void* out) {
  __shared__ __align__(16) char smem[32768 + 16 * XS * 2 + 16 * HS * 2];
  cg::grid_group grid = cg::this_grid();
  if (detect_f32(xabs))  // grid-uniform branch: grid.sync() is safe inside
    run_all<true>(xabs, h0, Wemb, bemb, Wsoc, bsoc, Wih, Whh, bih, bhh, c0,
                  Wout, bout, Z, Wih_b, Whh_b, Wout_b, out, smem, grid);
  else
    run_all<false>(xabs, h0, Wemb, bemb, Wsoc, bsoc, Wih, Whh, bih, bhh, c0,
                   Wout, bout, Z, Wih_b, Whh_b, Wout_b, out, smem, grid);
}

// ---------------------------------------------------------------------------
extern "C" void kernel_launch(void* const* d_in, const int* in_sizes, int n_in,
                              void* d_out, int out_size, void* d_ws, size_t ws_size,
                              hipStream_t stream) {
  const void* xabs = d_in[0];
  const void* h0   = d_in[1];
  const void* c0   = d_in[2];
  const void* Wemb = d_in[3];
  const void* bemb = d_in[4];
  const void* Wsoc = d_in[5];
  const void* bsoc = d_in[6];
  const void* Wih  = d_in[7];
  const void* Whh  = d_in[8];
  const void* bih  = d_in[9];
  const void* bhh  = d_in[10];
  const void* Wout = d_in[11];
  const void* bout = d_in[12];

  // ws: Z bf16[1024*4096] | Wih_b | Whh_b | Wout_b
  bf16* Z      = (bf16*)d_ws;
  bf16* Wih_b  = Z + (size_t)1024 * 4096;
  bf16* Whh_b  = Wih_b + (size_t)512 * 128;
  bf16* Wout_b = Whh_b + (size_t)512 * 128;
  void* outp   = d_out;

  void* args[] = {&xabs, &h0,  &Wemb, &bemb, &Wsoc,  &bsoc,  &Wih,
                  &Whh,  &bih, &bhh,  &c0,   &Wout,  &bout,  &Z,
                  &Wih_b, &Whh_b, &Wout_b, &outp};
  hipLaunchCooperativeKernel((void*)k_all, dim3(256), dim3(256), args, 0,
                             stream);
}

// Round 3
// 119.748 us; speedup vs baseline: 1.4563x; 1.4563x over previous
//
#include <hip/hip_runtime.h>
#include <hip/hip_bf16.h>
#include <math.h>

typedef __hip_bfloat16 bf16;
typedef short s8v __attribute__((ext_vector_type(8)));   // 8 bf16 (4 VGPRs)
typedef float f4v __attribute__((ext_vector_type(4)));   // MFMA acc

__device__ __forceinline__ float b2f(bf16 v) { return __bfloat162float(v); }

template <bool F32>
__device__ __forceinline__ float ld(const void* p, int i) {
  if (F32) return ((const float*)p)[i];
  return b2f(((const bf16*)p)[i]);
}

// 8 consecutive elems as a bf16x8 MFMA fragment (f32: 2 float4 + cvt).
template <bool F32>
__device__ __forceinline__ s8v ldfrag(const void* p, size_t i) {
  if (F32) {
    const float* f = (const float*)p + i;
    float4 u = *reinterpret_cast<const float4*>(f);
    float4 v = *reinterpret_cast<const float4*>(f + 4);
    s8v r;
    bf16 t;
    t = __float2bfloat16(u.x); r[0] = *(short*)&t;
    t = __float2bfloat16(u.y); r[1] = *(short*)&t;
    t = __float2bfloat16(u.z); r[2] = *(short*)&t;
    t = __float2bfloat16(u.w); r[3] = *(short*)&t;
    t = __float2bfloat16(v.x); r[4] = *(short*)&t;
    t = __float2bfloat16(v.y); r[5] = *(short*)&t;
    t = __float2bfloat16(v.z); r[6] = *(short*)&t;
    t = __float2bfloat16(v.w); r[7] = *(short*)&t;
    return r;
  }
  return *reinterpret_cast<const s8v*>((const bf16*)p + i);
}

__device__ __forceinline__ float sigm(float x) {
  return 0.5f * (1.0f + tanhf(0.5f * x));
}

// Wave-uniform dtype detect (validated R2-R7 of prior session).
__device__ __forceinline__ bool detect_f32(const void* xabs) {
  unsigned short v = ((const unsigned short*)xabs)[threadIdx.x & 63];
  int ex = (v >> 7) & 0xFF;
  return __ballot(ex >= 0x93) != 0ull;
}

// ---------------------------------------------------------------------------
// K1: 256 blocks. Each block: (a) <=1 float4/thread of weight cvt (folded in,
// block-uniform branch), then (b) Z = h0 @ Wsoc^T tile (64m x 256e, MFMA).
// ---------------------------------------------------------------------------
template <bool F32>
__device__ __forceinline__ void cvt_f4(const void* src, bf16* __restrict__ dst,
                                       int i4) {
  if (F32) {
    float4 v = reinterpret_cast<const float4*>(src)[i4];
    bf16 t[4] = {__float2bfloat16(v.x), __float2bfloat16(v.y),
                 __float2bfloat16(v.z), __float2bfloat16(v.w)};
    reinterpret_cast<uint2*>(dst)[i4] = *reinterpret_cast<uint2*>(t);
  } else {
    reinterpret_cast<uint2*>(dst)[i4] = reinterpret_cast<const uint2*>(src)[i4];
  }
}

template <bool F32>
__device__ __forceinline__ void zgemm_body(const void* h0, const void* Wsoc,
                                           const void* Wih, const void* Whh,
                                           const void* Wout,
                                           bf16* __restrict__ Z, bf16* Wih_b,
                                           bf16* Whh_b, bf16* Wout_b) {
  // Folded weight conversion: Wih 16384 f4 | Whh 16384 f4 | Wout 3840 f4.
  const int t4 = blockIdx.x * 256 + threadIdx.x;
  if (t4 < 16384)
    cvt_f4<F32>(Wih, Wih_b, t4);
  else if (t4 < 32768)
    cvt_f4<F32>(Whh, Whh_b, t4 - 16384);
  else if (t4 < 36608)
    cvt_f4<F32>(Wout, Wout_b, t4 - 32768);

  const int wave = threadIdx.x >> 6, lane = threadIdx.x & 63;
  const int mt = blockIdx.x & 15;               // 16 m-tiles of 64 rows
  const int g  = (blockIdx.x >> 4) * 4 + wave;  // 64 g's
  const int r16 = lane & 15, quad = lane >> 4;

  s8v afr[4][4];  // [ms][kq]
#pragma unroll
  for (int ms = 0; ms < 4; ++ms)
#pragma unroll
    for (int kq = 0; kq < 4; ++kq)
      afr[ms][kq] = ldfrag<F32>(
          h0, (size_t)(mt * 64 + ms * 16 + r16) * 128 + kq * 32 + quad * 8);

  f4v acc[4][4];  // [ms][t]
#pragma unroll
  for (int ms = 0; ms < 4; ++ms)
#pragma unroll
    for (int t = 0; t < 4; ++t) acc[ms][t] = (f4v){0.f, 0.f, 0.f, 0.f};

#pragma unroll
  for (int t = 0; t < 4; ++t) {
#pragma unroll
    for (int kq = 0; kq < 4; ++kq) {
      s8v bfr = ldfrag<F32>(
          Wsoc, (size_t)(t * 16 + r16) * 8192 + g * 128 + kq * 32 + quad * 8);
#pragma unroll
      for (int ms = 0; ms < 4; ++ms)
        acc[ms][t] = __builtin_amdgcn_mfma_f32_16x16x32_bf16(afr[ms][kq], bfr,
                                                             acc[ms][t], 0, 0, 0);
    }
  }
#pragma unroll
  for (int ms = 0; ms < 4; ++ms)
#pragma unroll
    for (int t = 0; t < 4; ++t)
#pragma unroll
      for (int reg = 0; reg < 4; ++reg)
        Z[(size_t)(mt * 64 + ms * 16 + quad * 4 + reg) * 4096 + g * 64 +
          t * 16 + r16] = __float2bfloat16(acc[ms][t][reg]);
}

__global__ __launch_bounds__(256, 1) void k_zgemm(
    const void* h0, const void* Wsoc, const void* Wih, const void* Whh,
    const void* Wout, bf16* __restrict__ Z, bf16* Wih_b, bf16* Whh_b,
    bf16* Wout_b, const void* xabs) {
  if (detect_f32(xabs))
    zgemm_body<true>(h0, Wsoc, Wih, Whh, Wout, Z, Wih_b, Whh_b, Wout_b);
  else
    zgemm_body<false>(h0, Wsoc, Wih, Whh, Wout, Z, Wih_b, Whh_b, Wout_b);
}

// ---------------------------------------------------------------------------
// K2 (fused): block = 4 n's. gather -> gates MFMA -> LSTM -> out MFMA.
// LDS: [0,32K) G f32[16][512] (aliases lists[4][1024] in gather phase)
//      Xb bf16[16][264] (padded), Hb bf16[16][136] (padded)
// Gather: dword loads, half-wave row pairing (lo lanes = neighbor i, hi lanes
// = neighbor i+1; each lane covers 2 of 64 E-columns). 16-deep unroll ->
// 32 neighbors per latency round trip (~4 trips at avg cnt~133).
// List build: xabs loads hoisted into an unrolled prologue (32 in flight).
// ---------------------------------------------------------------------------
#define XS 264
#define HS 136

template <bool F32>
__device__ __forceinline__ void fused_body(
    const void* xabs, const void* h0, const void* Wemb, const void* bemb,
    const void* bsoc, const bf16* __restrict__ Wih_b,
    const bf16* __restrict__ Whh_b, const void* bih, const void* bhh,
    const void* c0, const bf16* __restrict__ Wout_b, const void* bout,
    const bf16* __restrict__ Z, void* out, char* smem) {
  float* G   = (float*)smem;           // [16][512]
  int* lists = (int*)smem;             // [4][1024] (gather phase only)
  bf16* Xb   = (bf16*)(smem + 32768);  // [16][XS]
  bf16* Hb   = (bf16*)(smem + 32768 + 16 * XS * 2);  // [16][HS]
  const int tid = threadIdx.x;
  const int wave = tid >> 6, lane = tid & 63;
  const int r16 = lane & 15, quad = lane >> 4;
  const int l31 = lane & 31, half = lane >> 5;

  for (int idx = 4 * XS + tid; idx < 16 * XS; idx += 256)
    Xb[idx] = __float2bfloat16(0.f);
  for (int idx = 4 * HS + tid; idx < 16 * HS; idx += 256)
    Hb[idx] = __float2bfloat16(0.f);

  // ---- list build (loads hoisted, 32 independent in flight) ----
  const int n = blockIdx.x * 4 + wave;
  const float xn = ld<F32>(xabs, 2 * n);
  const float yn = ld<F32>(xabs, 2 * n + 1);
  const float tx = xn - 0.2f, ty = yn - 0.2f;
  float dxs[16], dys[16];
#pragma unroll
  for (int c = 0; c < 16; ++c) {
    const int m = c * 64 + lane;
    dxs[c] = ld<F32>(xabs, 2 * m) - tx;
    dys[c] = ld<F32>(xabs, 2 * m + 1) - ty;
  }
  int* mylist = lists + wave * 1024;
  int cnt = 0;
#pragma unroll
  for (int c = 0; c < 16; ++c) {
    const int m = c * 64 + lane;
    float dx = dxs[c], dy = dys[c];
    int cx = (int)floorf(dx / 0.4f * 8.0f);
    int cy = (int)floorf(dy / 0.4f * 8.0f);
    bool valid = (dx >= 0.f) & (dx < 0.4f) & (dy >= 0.f) & (dy < 0.4f) &
                 (cx >= 0) & (cx < 8) & (cy >= 0) & (cy < 8) & (m != n);
    unsigned long long msk = __ballot(valid);
    if (valid) {
      int pos = cnt + __popcll(msk & ((1ull << lane) - 1ull));
      mylist[pos] = (m << 6) | (cx + cy * 8);
    }
    cnt += __popcll(msk);
  }

  // ---- Z-independent staging (issue loads before gather) ----
  float emb = fmaxf(ld<F32>(Wemb, lane * 2) * xn +
                        ld<F32>(Wemb, lane * 2 + 1) * yn + ld<F32>(bemb, lane),
                    0.f);
  Xb[wave * XS + lane] = __float2bfloat16(emb);
  Xb[wave * XS + 128 + lane] = __float2bfloat16(ld<F32>(h0, n * 128 + lane));
  Xb[wave * XS + 192 + lane] =
      __float2bfloat16(ld<F32>(h0, n * 128 + 64 + lane));

  // ---- gather (dword, half-wave row pairing) ----
  // lane covers columns e = l31*2, l31*2+1 ; half 0 handles even-list rows,
  // half 1 odd-list rows; cross-half combine at the end via shfl_xor(32).
  float ax[16], ay[16];
#pragma unroll
  for (int u = 0; u < 16; ++u) { ax[u] = 0.f; ay[u] = 0.f; }
  int i = 0;
  for (; i + 32 <= cnt; i += 32) {
    int e[16];
#pragma unroll
    for (int u = 0; u < 16; ++u) e[u] = mylist[i + 2 * u + half];
#pragma unroll
    for (int u = 0; u < 16; ++u) {
      unsigned d = *reinterpret_cast<const unsigned*>(
          &Z[(size_t)(e[u] >> 6) * 4096 + ((e[u] & 63) << 6) + (l31 << 1)]);
      ax[u] += __uint_as_float(d << 16);
      ay[u] += __uint_as_float(d & 0xffff0000u);
    }
  }
  for (; i + 8 <= cnt; i += 8) {
    int e[4];
#pragma unroll
    for (int u = 0; u < 4; ++u) e[u] = mylist[i + 2 * u + half];
#pragma unroll
    for (int u = 0; u < 4; ++u) {
      unsigned d = *reinterpret_cast<const unsigned*>(
          &Z[(size_t)(e[u] >> 6) * 4096 + ((e[u] & 63) << 6) + (l31 << 1)]);
      ax[u] += __uint_as_float(d << 16);
      ay[u] += __uint_as_float(d & 0xffff0000u);
    }
  }
  for (; i + 2 <= cnt; i += 2) {
    int e0 = mylist[i + half];
    unsigned d = *reinterpret_cast<const unsigned*>(
        &Z[(size_t)(e0 >> 6) * 4096 + ((e0 & 63) << 6) + (l31 << 1)]);
    ax[0] += __uint_as_float(d << 16);
    ay[0] += __uint_as_float(d & 0xffff0000u);
  }
  if (i < cnt) {  // single leftover row: low half only
    int e0 = mylist[i];
    if (half == 0) {
      unsigned d = *reinterpret_cast<const unsigned*>(
          &Z[(size_t)(e0 >> 6) * 4096 + ((e0 & 63) << 6) + (l31 << 1)]);
      ax[0] += __uint_as_float(d << 16);
      ay[0] += __uint_as_float(d & 0xffff0000u);
    }
  }
#pragma unroll
  for (int u = 8; u < 16; ++u) { ax[u - 8] += ax[u]; ay[u - 8] += ay[u]; }
#pragma unroll
  for (int u = 4; u < 8; ++u) { ax[u - 4] += ax[u]; ay[u - 4] += ay[u]; }
  float sx = (ax[0] + ax[1]) + (ax[2] + ax[3]);
  float sy = (ay[0] + ay[1]) + (ay[2] + ay[3]);
  sx += __shfl_xor(sx, 32);
  sy += __shfl_xor(sy, 32);
  if (half == 0) {
    float p0 = fmaxf(sx + ld<F32>(bsoc, l31 * 2), 0.f);
    float p1 = fmaxf(sy + ld<F32>(bsoc, l31 * 2 + 1), 0.f);
    Xb[wave * XS + 64 + l31 * 2] = __float2bfloat16(p0);
    Xb[wave * XS + 64 + l31 * 2 + 1] = __float2bfloat16(p1);
  }
  __syncthreads();  // lists dead; G live from here

  // ---- gates MFMA ----
  s8v xfr[8];
#pragma unroll
  for (int kq = 0; kq < 8; ++kq)
    xfr[kq] = *reinterpret_cast<const s8v*>(&Xb[r16 * XS + kq * 32 + quad * 8]);
  const int j0w = wave * 128;
  f4v bacc[8];
#pragma unroll
  for (int jt = 0; jt < 8; ++jt) bacc[jt] = (f4v){0.f, 0.f, 0.f, 0.f};
#pragma unroll
  for (int jt = 0; jt < 8; ++jt) {
    int j = j0w + jt * 16 + r16;
#pragma unroll
    for (int kq = 0; kq < 4; ++kq) {
      s8v bfr = *reinterpret_cast<const s8v*>(
          &Wih_b[(size_t)j * 128 + kq * 32 + quad * 8]);
      bacc[jt] = __builtin_amdgcn_mfma_f32_16x16x32_bf16(xfr[kq], bfr, bacc[jt],
                                                         0, 0, 0);
    }
#pragma unroll
    for (int kq = 0; kq < 4; ++kq) {
      s8v bfr = *reinterpret_cast<const s8v*>(
          &Whh_b[(size_t)j * 128 + kq * 32 + quad * 8]);
      bacc[jt] = __builtin_amdgcn_mfma_f32_16x16x32_bf16(xfr[kq + 4], bfr,
                                                         bacc[jt], 0, 0, 0);
    }
  }
#pragma unroll
  for (int jt = 0; jt < 8; ++jt) {
    int j = j0w + jt * 16 + r16;
    float bias = ld<F32>(bih, j) + ld<F32>(bhh, j);
#pragma unroll
    for (int reg = 0; reg < 4; ++reg)
      G[(quad * 4 + reg) * 512 + j] = bacc[jt][reg] + bias;
  }
  __syncthreads();

  // ---- LSTM elementwise ----
  for (int idx = tid; idx < 512; idx += 256) {
    int m = idx >> 7, tt = idx & 127;
    float ig = G[m * 512 + tt], fg = G[m * 512 + 128 + tt];
    float gg = G[m * 512 + 256 + tt], og = G[m * 512 + 384 + tt];
    float c = sigm(fg) * ld<F32>(c0, (blockIdx.x * 4 + m) * 128 + tt) +
              sigm(ig) * tanhf(gg);
    Hb[m * HS + tt] = __float2bfloat16(sigm(og) * tanhf(c));
  }
  __syncthreads();

  // ---- out MFMA ----
  s8v hfr[4];
#pragma unroll
  for (int kq = 0; kq < 4; ++kq)
    hfr[kq] = *reinterpret_cast<const s8v*>(&Hb[r16 * HS + kq * 32 + quad * 8]);
#pragma unroll
  for (int jt2 = 0; jt2 < 2; ++jt2) {
    int j = wave * 32 + jt2 * 16 + r16;
    int jj = j < 120 ? j : 119;
    f4v oacc = (f4v){0.f, 0.f, 0.f, 0.f};
#pragma unroll
    for (int kq = 0; kq < 4; ++kq) {
      s8v bfr = *reinterpret_cast<const s8v*>(
          &Wout_b[(size_t)jj * 128 + kq * 32 + quad * 8]);
      oacc = __builtin_amdgcn_mfma_f32_16x16x32_bf16(hfr[kq], bfr, oacc, 0, 0, 0);
    }
    if (j < 120 && quad == 0) {
      float bo = ld<F32>(bout, j);
      int kk = j / 20, mm = j % 20;
#pragma unroll
      for (int reg = 0; reg < 4; ++reg) {
        int oi = kk * 20480 + (blockIdx.x * 4 + reg) * 20 + mm;
        float val = oacc[reg] + bo;
        if (F32) ((float*)out)[oi] = val;
        else     ((bf16*)out)[oi] = __float2bfloat16(val);
      }
    }
  }
}

__global__ __launch_bounds__(256, 1) void k_fused(
    const void* xabs, const void* h0, const void* Wemb, const void* bemb,
    const void* bsoc, const bf16* Wih_b, const bf16* Whh_b, const void* bih,
    const void* bhh, const void* c0, const bf16* Wout_b, const void* bout,
    const bf16* __restrict__ Z, void* out) {
  __shared__ __align__(16) char smem[32768 + 16 * XS * 2 + 16 * HS * 2];
  if (detect_f32(xabs))
    fused_body<true>(xabs, h0, Wemb, bemb, bsoc, Wih_b, Whh_b, bih, bhh, c0,
                     Wout_b, bout, Z, out, smem);
  else
    fused_body<false>(xabs, h0, Wemb, bemb, bsoc, Wih_b, Whh_b, bih, bhh, c0,
                      Wout_b, bout, Z, out, smem);
}

// ---------------------------------------------------------------------------
extern "C" void kernel_launch(void* const* d_in, const int* in_sizes, int n_in,
                              void* d_out, int out_size, void* d_ws, size_t ws_size,
                              hipStream_t stream) {
  const void* xabs = d_in[0];
  const void* h0   = d_in[1];
  const void* c0   = d_in[2];
  const void* Wemb = d_in[3];
  const void* bemb = d_in[4];
  const void* Wsoc = d_in[5];
  const void* bsoc = d_in[6];
  const void* Wih  = d_in[7];
  const void* Whh  = d_in[8];
  const void* bih  = d_in[9];
  const void* bhh  = d_in[10];
  const void* Wout = d_in[11];
  const void* bout = d_in[12];

  // ws: Z bf16[1024*4096] | Wih_b | Whh_b | Wout_b
  bf16* Z      = (bf16*)d_ws;
  bf16* Wih_b  = Z + (size_t)1024 * 4096;
  bf16* Whh_b  = Wih_b + (size_t)512 * 128;
  bf16* Wout_b = Whh_b + (size_t)512 * 128;

  k_zgemm<<<dim3(256), dim3(256), 0, stream>>>(h0, Wsoc, Wih, Whh, Wout, Z,
                                               Wih_b, Whh_b, Wout_b, xabs);
  k_fused<<<dim3(256), dim3(256), 0, stream>>>(xabs, h0, Wemb, bemb, bsoc,
                                               Wih_b, Whh_b, bih, bhh, c0,
                                               Wout_b, bout, Z, d_out);
}

// Round 4
// 112.318 us; speedup vs baseline: 1.5526x; 1.0662x over previous
//
#include <hip/hip_runtime.h>
#include <hip/hip_bf16.h>
#include <math.h>

typedef __hip_bfloat16 bf16;
typedef short s8v __attribute__((ext_vector_type(8)));      // 8 bf16 (4 VGPRs)
typedef float f4v __attribute__((ext_vector_type(4)));      // MFMA acc
typedef unsigned u4v __attribute__((ext_vector_type(4)));   // 4 dwords

__device__ __forceinline__ float b2f(bf16 v) { return __bfloat162float(v); }

template <bool F32>
__device__ __forceinline__ float ld(const void* p, int i) {
  if (F32) return ((const float*)p)[i];
  return b2f(((const bf16*)p)[i]);
}

// 8 consecutive elems as a bf16x8 MFMA fragment (f32: 2 float4 + cvt).
template <bool F32>
__device__ __forceinline__ s8v ldfrag(const void* p, size_t i) {
  if (F32) {
    const float* f = (const float*)p + i;
    float4 u = *reinterpret_cast<const float4*>(f);
    float4 v = *reinterpret_cast<const float4*>(f + 4);
    s8v r;
    bf16 t;
    t = __float2bfloat16(u.x); r[0] = *(short*)&t;
    t = __float2bfloat16(u.y); r[1] = *(short*)&t;
    t = __float2bfloat16(u.z); r[2] = *(short*)&t;
    t = __float2bfloat16(u.w); r[3] = *(short*)&t;
    t = __float2bfloat16(v.x); r[4] = *(short*)&t;
    t = __float2bfloat16(v.y); r[5] = *(short*)&t;
    t = __float2bfloat16(v.z); r[6] = *(short*)&t;
    t = __float2bfloat16(v.w); r[7] = *(short*)&t;
    return r;
  }
  return *reinterpret_cast<const s8v*>((const bf16*)p + i);
}

// Fast sigmoid/tanh via hw exp + rcp. Robust at +/-inf (exp->0 or inf).
// Error ~1e-7, far below the bf16-dominated output tolerance.
__device__ __forceinline__ float sigm(float x) {
  return __builtin_amdgcn_rcpf(1.0f + __expf(-x));
}
__device__ __forceinline__ float ftanh(float x) {
  return 1.0f - 2.0f * __builtin_amdgcn_rcpf(1.0f + __expf(2.0f * x));
}

// Wave-uniform dtype detect (validated R2-R7 of prior session).
__device__ __forceinline__ bool detect_f32(const void* xabs) {
  unsigned short v = ((const unsigned short*)xabs)[threadIdx.x & 63];
  int ex = (v >> 7) & 0xFF;
  return __ballot(ex >= 0x93) != 0ull;
}

// ---------------------------------------------------------------------------
// K1: 256 blocks. Each block: (a) <=1 float4/thread of weight cvt (folded in,
// block-uniform branch), then (b) Z = h0 @ Wsoc^T tile (64m x 256e, MFMA).
// Block 0 additionally zeroes the 128-byte gather pad row Z[1024][0..63].
// ---------------------------------------------------------------------------
template <bool F32>
__device__ __forceinline__ void cvt_f4(const void* src, bf16* __restrict__ dst,
                                       int i4) {
  if (F32) {
    float4 v = reinterpret_cast<const float4*>(src)[i4];
    bf16 t[4] = {__float2bfloat16(v.x), __float2bfloat16(v.y),
                 __float2bfloat16(v.z), __float2bfloat16(v.w)};
    reinterpret_cast<uint2*>(dst)[i4] = *reinterpret_cast<uint2*>(t);
  } else {
    reinterpret_cast<uint2*>(dst)[i4] = reinterpret_cast<const uint2*>(src)[i4];
  }
}

template <bool F32>
__device__ __forceinline__ void zgemm_body(const void* h0, const void* Wsoc,
                                           const void* Wih, const void* Whh,
                                           const void* Wout,
                                           bf16* __restrict__ Z, bf16* Wih_b,
                                           bf16* Whh_b, bf16* Wout_b) {
  // Folded weight conversion: Wih 16384 f4 | Whh 16384 f4 | Wout 3840 f4.
  const int t4 = blockIdx.x * 256 + threadIdx.x;
  if (t4 < 16384)
    cvt_f4<F32>(Wih, Wih_b, t4);
  else if (t4 < 32768)
    cvt_f4<F32>(Whh, Whh_b, t4 - 16384);
  else if (t4 < 36608)
    cvt_f4<F32>(Wout, Wout_b, t4 - 32768);

  // Zero pad row Z[1024][0..63] (gather dummy target): 128 B.
  if (blockIdx.x == 0 && threadIdx.x < 16)
    reinterpret_cast<uint2*>(Z + (size_t)1024 * 4096)[threadIdx.x] =
        (uint2){0u, 0u};

  const int wave = threadIdx.x >> 6, lane = threadIdx.x & 63;
  const int mt = blockIdx.x & 15;               // 16 m-tiles of 64 rows
  const int g  = (blockIdx.x >> 4) * 4 + wave;  // 64 g's
  const int r16 = lane & 15, quad = lane >> 4;

  s8v afr[4][4];  // [ms][kq]
#pragma unroll
  for (int ms = 0; ms < 4; ++ms)
#pragma unroll
    for (int kq = 0; kq < 4; ++kq)
      afr[ms][kq] = ldfrag<F32>(
          h0, (size_t)(mt * 64 + ms * 16 + r16) * 128 + kq * 32 + quad * 8);

  f4v acc[4][4];  // [ms][t]
#pragma unroll
  for (int ms = 0; ms < 4; ++ms)
#pragma unroll
    for (int t = 0; t < 4; ++t) acc[ms][t] = (f4v){0.f, 0.f, 0.f, 0.f};

#pragma unroll
  for (int t = 0; t < 4; ++t) {
#pragma unroll
    for (int kq = 0; kq < 4; ++kq) {
      s8v bfr = ldfrag<F32>(
          Wsoc, (size_t)(t * 16 + r16) * 8192 + g * 128 + kq * 32 + quad * 8);
#pragma unroll
      for (int ms = 0; ms < 4; ++ms)
        acc[ms][t] = __builtin_amdgcn_mfma_f32_16x16x32_bf16(afr[ms][kq], bfr,
                                                             acc[ms][t], 0, 0, 0);
    }
  }
#pragma unroll
  for (int ms = 0; ms < 4; ++ms)
#pragma unroll
    for (int t = 0; t < 4; ++t)
#pragma unroll
      for (int reg = 0; reg < 4; ++reg)
        Z[(size_t)(mt * 64 + ms * 16 + quad * 4 + reg) * 4096 + g * 64 +
          t * 16 + r16] = __float2bfloat16(acc[ms][t][reg]);
}

__global__ __launch_bounds__(256, 1) void k_zgemm(
    const void* h0, const void* Wsoc, const void* Wih, const void* Whh,
    const void* Wout, bf16* __restrict__ Z, bf16* Wih_b, bf16* Whh_b,
    bf16* Wout_b, const void* xabs) {
  if (detect_f32(xabs))
    zgemm_body<true>(h0, Wsoc, Wih, Whh, Wout, Z, Wih_b, Whh_b, Wout_b);
  else
    zgemm_body<false>(h0, Wsoc, Wih, Whh, Wout, Z, Wih_b, Whh_b, Wout_b);
}

// ---------------------------------------------------------------------------
// K2 (fused): block = 4 n's. gather -> gates MFMA -> LSTM -> out MFMA.
// LDS: [0,32K) G f32[4][512] region (aliases lists[4][1024] in gather phase)
//      Xb bf16[16][264] (padded), Hb bf16[16][136] (padded)
// Gather: dwordx4 loads, 8 rows per wave-instruction (rowg=lane>>3 picks the
// list row, colg=lane&7 picks 8 of 64 E-cols). List padded to a multiple of
// 8 with entries pointing at zeroed Z[1024]; 128-row main block keeps 16
// loads in flight (1 trip), uniform-predicated tail issues the rest together
// -> ~2 L2 round trips at avg cnt~133 (was ~4-5).
// ---------------------------------------------------------------------------
#define XS 264
#define HS 136

template <bool F32>
__device__ __forceinline__ void fused_body(
    const void* xabs, const void* h0, const void* Wemb, const void* bemb,
    const void* bsoc, const bf16* __restrict__ Wih_b,
    const bf16* __restrict__ Whh_b, const void* bih, const void* bhh,
    const void* c0, const bf16* __restrict__ Wout_b, const void* bout,
    const bf16* __restrict__ Z, void* out, char* smem) {
  float* G   = (float*)smem;           // [4][512] used (rows 0-3)
  int* lists = (int*)smem;             // [4][1024] (gather phase only)
  bf16* Xb   = (bf16*)(smem + 32768);  // [16][XS]
  bf16* Hb   = (bf16*)(smem + 32768 + 16 * XS * 2);  // [16][HS]
  const int tid = threadIdx.x;
  const int wave = tid >> 6, lane = tid & 63;
  const int r16 = lane & 15, quad = lane >> 4;
  const int rowg = lane >> 3, colg = lane & 7;

  for (int idx = 4 * XS + tid; idx < 16 * XS; idx += 256)
    Xb[idx] = __float2bfloat16(0.f);
  for (int idx = 4 * HS + tid; idx < 16 * HS; idx += 256)
    Hb[idx] = __float2bfloat16(0.f);

  // ---- list build (loads hoisted, 32 independent in flight) ----
  const int n = blockIdx.x * 4 + wave;
  const float xn = ld<F32>(xabs, 2 * n);
  const float yn = ld<F32>(xabs, 2 * n + 1);
  const float tx = xn - 0.2f, ty = yn - 0.2f;
  float dxs[16], dys[16];
#pragma unroll
  for (int c = 0; c < 16; ++c) {
    const int m = c * 64 + lane;
    dxs[c] = ld<F32>(xabs, 2 * m) - tx;
    dys[c] = ld<F32>(xabs, 2 * m + 1) - ty;
  }
  int* mylist = lists + wave * 1024;
  int cnt = 0;
#pragma unroll
  for (int c = 0; c < 16; ++c) {
    const int m = c * 64 + lane;
    float dx = dxs[c], dy = dys[c];
    int cx = (int)floorf(dx / 0.4f * 8.0f);
    int cy = (int)floorf(dy / 0.4f * 8.0f);
    bool valid = (dx >= 0.f) & (dx < 0.4f) & (dy >= 0.f) & (dy < 0.4f) &
                 (cx >= 0) & (cx < 8) & (cy >= 0) & (cy < 8) & (m != n);
    unsigned long long msk = __ballot(valid);
    if (valid) {
      int pos = cnt + __popcll(msk & ((1ull << lane) - 1ull));
      mylist[pos] = (m << 6) | (cx + cy * 8);
    }
    cnt += __popcll(msk);
  }
  // pad list to a multiple of 8 with dummies hitting the zero row Z[1024]
  const int padded = (cnt + 7) & ~7;
  if (cnt + lane < padded) mylist[cnt + lane] = (1024 << 6);

  // ---- Z-independent staging ----
  float emb = fmaxf(ld<F32>(Wemb, lane * 2) * xn +
                        ld<F32>(Wemb, lane * 2 + 1) * yn + ld<F32>(bemb, lane),
                    0.f);
  Xb[wave * XS + lane] = __float2bfloat16(emb);
  Xb[wave * XS + 128 + lane] = __float2bfloat16(ld<F32>(h0, n * 128 + lane));
  Xb[wave * XS + 192 + lane] =
      __float2bfloat16(ld<F32>(h0, n * 128 + 64 + lane));

  // ---- gather (dwordx4, 8 rows per wave-load) ----
  float ax[4], ay[4];  // ax[w]=col colg*8+2w, ay[w]=col colg*8+2w+1
#pragma unroll
  for (int w = 0; w < 4; ++w) { ax[w] = 0.f; ay[w] = 0.f; }
  int i = 0;
  for (; i + 128 <= padded; i += 128) {  // 16 loads in flight
    u4v d[16];
#pragma unroll
    for (int u = 0; u < 16; ++u) {
      int e = mylist[i + u * 8 + rowg];
      d[u] = *reinterpret_cast<const u4v*>(
          &Z[(size_t)(e >> 6) * 4096 + ((e & 63) << 6) + (colg << 3)]);
    }
#pragma unroll
    for (int u = 0; u < 16; ++u)
#pragma unroll
      for (int w = 0; w < 4; ++w) {
        ax[w] += __uint_as_float(d[u][w] << 16);
        ay[w] += __uint_as_float(d[u][w] & 0xffff0000u);
      }
  }
  int rem = padded - i;  // multiple of 8, 0..120
  if (rem >= 64) {       // 8 loads in flight
    u4v d[8];
#pragma unroll
    for (int u = 0; u < 8; ++u) {
      int e = mylist[i + u * 8 + rowg];
      d[u] = *reinterpret_cast<const u4v*>(
          &Z[(size_t)(e >> 6) * 4096 + ((e & 63) << 6) + (colg << 3)]);
    }
#pragma unroll
    for (int u = 0; u < 8; ++u)
#pragma unroll
      for (int w = 0; w < 4; ++w) {
        ax[w] += __uint_as_float(d[u][w] << 16);
        ay[w] += __uint_as_float(d[u][w] & 0xffff0000u);
      }
    i += 64;
    rem -= 64;
  }
  {  // uniform-predicated tail: ns in 0..7, all loads issued together
    const int ns = rem >> 3;
    u4v d[7];
#pragma unroll
    for (int u = 0; u < 7; ++u)
      if (u < ns) {
        int e = mylist[i + u * 8 + rowg];
        d[u] = *reinterpret_cast<const u4v*>(
            &Z[(size_t)(e >> 6) * 4096 + ((e & 63) << 6) + (colg << 3)]);
      }
#pragma unroll
    for (int u = 0; u < 7; ++u)
      if (u < ns)
#pragma unroll
        for (int w = 0; w < 4; ++w) {
          ax[w] += __uint_as_float(d[u][w] << 16);
          ay[w] += __uint_as_float(d[u][w] & 0xffff0000u);
        }
  }
  // reduce across the 8 row-groups (lane bits 3..5)
#pragma unroll
  for (int mks = 8; mks <= 32; mks <<= 1)
#pragma unroll
    for (int w = 0; w < 4; ++w) {
      ax[w] += __shfl_xor(ax[w], mks);
      ay[w] += __shfl_xor(ay[w], mks);
    }
  if (rowg == 0) {  // lanes 0..7: lane colg writes cols colg*8..colg*8+7
#pragma unroll
    for (int w = 0; w < 4; ++w) {
      int c0 = colg * 8 + 2 * w;
      Xb[wave * XS + 64 + c0] =
          __float2bfloat16(fmaxf(ax[w] + ld<F32>(bsoc, c0), 0.f));
      Xb[wave * XS + 64 + c0 + 1] =
          __float2bfloat16(fmaxf(ay[w] + ld<F32>(bsoc, c0 + 1), 0.f));
    }
  }
  __syncthreads();  // lists dead; G live from here

  // ---- gates MFMA ----
  s8v xfr[8];
#pragma unroll
  for (int kq = 0; kq < 8; ++kq)
    xfr[kq] = *reinterpret_cast<const s8v*>(&Xb[r16 * XS + kq * 32 + quad * 8]);
  const int j0w = wave * 128;
  f4v bacc[8];
#pragma unroll
  for (int jt = 0; jt < 8; ++jt) bacc[jt] = (f4v){0.f, 0.f, 0.f, 0.f};
#pragma unroll
  for (int jt = 0; jt < 8; ++jt) {
    int j = j0w + jt * 16 + r16;
#pragma unroll
    for (int kq = 0; kq < 4; ++kq) {
      s8v bfr = *reinterpret_cast<const s8v*>(
          &Wih_b[(size_t)j * 128 + kq * 32 + quad * 8]);
      bacc[jt] = __builtin_amdgcn_mfma_f32_16x16x32_bf16(xfr[kq], bfr, bacc[jt],
                                                         0, 0, 0);
    }
#pragma unroll
    for (int kq = 0; kq < 4; ++kq) {
      s8v bfr = *reinterpret_cast<const s8v*>(
          &Whh_b[(size_t)j * 128 + kq * 32 + quad * 8]);
      bacc[jt] = __builtin_amdgcn_mfma_f32_16x16x32_bf16(xfr[kq + 4], bfr,
                                                         bacc[jt], 0, 0, 0);
    }
  }
  // only rows 0-3 are real n's (quad==0 lanes hold them)
  if (quad == 0) {
#pragma unroll
    for (int jt = 0; jt < 8; ++jt) {
      int j = j0w + jt * 16 + r16;
      float bias = ld<F32>(bih, j) + ld<F32>(bhh, j);
#pragma unroll
      for (int reg = 0; reg < 4; ++reg)
        G[reg * 512 + j] = bacc[jt][reg] + bias;
    }
  }
  __syncthreads();

  // ---- LSTM elementwise ----
  for (int idx = tid; idx < 512; idx += 256) {
    int m = idx >> 7, tt = idx & 127;
    float ig = G[m * 512 + tt], fg = G[m * 512 + 128 + tt];
    float gg = G[m * 512 + 256 + tt], og = G[m * 512 + 384 + tt];
    float c = sigm(fg) * ld<F32>(c0, (blockIdx.x * 4 + m) * 128 + tt) +
              sigm(ig) * ftanh(gg);
    Hb[m * HS + tt] = __float2bfloat16(sigm(og) * ftanh(c));
  }
  __syncthreads();

  // ---- out MFMA ----
  s8v hfr[4];
#pragma unroll
  for (int kq = 0; kq < 4; ++kq)
    hfr[kq] = *reinterpret_cast<const s8v*>(&Hb[r16 * HS + kq * 32 + quad * 8]);
#pragma unroll
  for (int jt2 = 0; jt2 < 2; ++jt2) {
    int j = wave * 32 + jt2 * 16 + r16;
    int jj = j < 120 ? j : 119;
    f4v oacc = (f4v){0.f, 0.f, 0.f, 0.f};
#pragma unroll
    for (int kq = 0; kq < 4; ++kq) {
      s8v bfr = *reinterpret_cast<const s8v*>(
          &Wout_b[(size_t)jj * 128 + kq * 32 + quad * 8]);
      oacc = __builtin_amdgcn_mfma_f32_16x16x32_bf16(hfr[kq], bfr, oacc, 0, 0, 0);
    }
    if (j < 120 && quad == 0) {
      float bo = ld<F32>(bout, j);
      int kk = j / 20, mm = j % 20;
#pragma unroll
      for (int reg = 0; reg < 4; ++reg) {
        int oi = kk * 20480 + (blockIdx.x * 4 + reg) * 20 + mm;
        float val = oacc[reg] + bo;
        if (F32) ((float*)out)[oi] = val;
        else     ((bf16*)out)[oi] = __float2bfloat16(val);
      }
    }
  }
}

__global__ __launch_bounds__(256, 1) void k_fused(
    const void* xabs, const void* h0, const void* Wemb, const void* bemb,
    const void* bsoc, const bf16* Wih_b, const bf16* Whh_b, const void* bih,
    const void* bhh, const void* c0, const bf16* Wout_b, const void* bout,
    const bf16* __restrict__ Z, void* out) {
  __shared__ __align__(16) char smem[32768 + 16 * XS * 2 + 16 * HS * 2];
  if (detect_f32(xabs))
    fused_body<true>(xabs, h0, Wemb, bemb, bsoc, Wih_b, Whh_b, bih, bhh, c0,
                     Wout_b, bout, Z, out, smem);
  else
    fused_body<false>(xabs, h0, Wemb, bemb, bsoc, Wih_b, Whh_b, bih, bhh, c0,
                      Wout_b, bout, Z, out, smem);
}

// ---------------------------------------------------------------------------
extern "C" void kernel_launch(void* const* d_in, const int* in_sizes, int n_in,
                              void* d_out, int out_size, void* d_ws, size_t ws_size,
                              hipStream_t stream) {
  const void* xabs = d_in[0];
  const void* h0   = d_in[1];
  const void* c0   = d_in[2];
  const void* Wemb = d_in[3];
  const void* bemb = d_in[4];
  const void* Wsoc = d_in[5];
  const void* bsoc = d_in[6];
  const void* Wih  = d_in[7];
  const void* Whh  = d_in[8];
  const void* bih  = d_in[9];
  const void* bhh  = d_in[10];
  const void* Wout = d_in[11];
  const void* bout = d_in[12];

  // ws: Z bf16[1025*4096] (row 1024 = zero pad row) | Wih_b | Whh_b | Wout_b
  bf16* Z      = (bf16*)d_ws;
  bf16* Wih_b  = Z + (size_t)1025 * 4096;
  bf16* Whh_b  = Wih_b + (size_t)512 * 128;
  bf16* Wout_b = Whh_b + (size_t)512 * 128;

  k_zgemm<<<dim3(256), dim3(256), 0, stream>>>(h0, Wsoc, Wih, Whh, Wout, Z,
                                               Wih_b, Whh_b, Wout_b, xabs);
  k_fused<<<dim3(256), dim3(256), 0, stream>>>(xabs, h0, Wemb, bemb, bsoc,
                                               Wih_b, Whh_b, bih, bhh, c0,
                                               Wout_b, bout, Z, d_out);
}